// Round 17
// baseline (204.462 us; speedup 1.0000x reference)
//
#include <hip/hip_runtime.h>

#define NPTS 4096
#define DIM  256
#define TIL  64       // number of 64-wide col tiles
#define WCAND 32      // per-row candidate cap in row_kernel

typedef unsigned short u16;
typedef unsigned long long u64;
typedef __attribute__((ext_vector_type(8))) short bf16x8;
typedef __attribute__((ext_vector_type(4))) float f32x4;
typedef __attribute__((ext_vector_type(4))) unsigned short u16x4;

__device__ __forceinline__ float exp2fast(float x) {
  float r;
  asm("v_exp_f32 %0, %1" : "=v"(r) : "v"(x));
  return r;
}

__device__ __forceinline__ void gload_lds16(const void* g, void* l) {
  __builtin_amdgcn_global_load_lds((const __attribute__((address_space(1))) void*)g,
                                   (__attribute__((address_space(3))) void*)l, 16, 0, 0);
}

__device__ __forceinline__ float blk_sum4(float v, float* sh) {
  #pragma unroll
  for (int off = 32; off; off >>= 1) v += __shfl_down(v, off);
  int lane = threadIdx.x & 63, w = threadIdx.x >> 6;
  __syncthreads();
  if (lane == 0) sh[w] = v;
  __syncthreads();
  return sh[0] + sh[1] + sh[2] + sh[3];
}

__device__ __forceinline__ float blk_sum8(float v, float* sh) {
  #pragma unroll
  for (int off = 32; off; off >>= 1) v += __shfl_down(v, off);
  int lane = threadIdx.x & 63, w = threadIdx.x >> 6;
  __syncthreads();
  if (lane == 0) sh[w] = v;
  __syncthreads();
  return ((sh[0] + sh[1]) + (sh[2] + sh[3])) + ((sh[4] + sh[5]) + (sh[6] + sh[7]));
}

// per-block redundant scalesq for 256-thread blocks
__device__ __forceinline__ float block_scalesq(
    const float* __restrict__ bbp, const float* __restrict__ bbn, float* red, int tid) {
  float s = 0.f;
  #pragma unroll
  for (int q = 0; q < 4; ++q) {
    f32x4 a = *reinterpret_cast<const f32x4*>(bbp + (q * 256 + tid) * 4);
    f32x4 b = *reinterpret_cast<const f32x4*>(bbn + (q * 256 + tid) * 4);
    s += a[0] + a[1] + a[2] + a[3] + b[0] + b[1] + b[2] + b[3];
  }
  float tot = blk_sum4(s, red);
  return tot * (1.0f / (2.0f * NPTS * DIM)) + 1e-8f;
}

// ---------- K1: bf16 round + row sumsq for all three inputs ----------
__global__ __launch_bounds__(256) void split3_kernel(
    const float* __restrict__ x, const float* __restrict__ yp, const float* __restrict__ yn,
    u16* __restrict__ xb, u16* __restrict__ ypb, u16* __restrict__ ynb,
    float* __restrict__ bbp, float* __restrict__ bbn)
{
  const float* src; u16* dst; float* bb;
  if      (blockIdx.y == 0) { src = x;  dst = xb;  bb = nullptr; }
  else if (blockIdx.y == 1) { src = yp; dst = ypb; bb = bbp; }
  else                      { src = yn; dst = ynb; bb = bbn; }

  int lane = threadIdx.x & 63;
  int wave = threadIdx.x >> 6;
  int row  = blockIdx.x * 4 + wave;
  const float4 v = *reinterpret_cast<const float4*>(src + (size_t)row * DIM + lane * 4);
  float xs[4] = {v.x, v.y, v.z, v.w};
  u16x4 h;
  float ss = 0.f;
  #pragma unroll
  for (int e = 0; e < 4; ++e) {
    unsigned b = __float_as_uint(xs[e]);
    h[e] = (u16)((b + 0x7fffu + ((b >> 16) & 1u)) >> 16);   // bf16 RTNE
    ss += xs[e] * xs[e];
  }
  *reinterpret_cast<u16x4*>(dst + (size_t)row * DIM + lane * 4) = h;
  if (bb) {
    #pragma unroll
    for (int off = 32; off; off >>= 1) ss += __shfl_down(ss, off);
    if (lane == 0) bb[row] = ss;
  }
}

// ---------- K2: bf16 GEMM 256x256, 8 waves (2x4), BK=32 dbuf, mask epilogue ----------
// per step: barrier -> STAGE(ks+1) -> vmcnt(4) -> ds_read(cur) -> 32 MFMA.
__global__ __launch_bounds__(512, 4) void gemm_kernel(
    const u16* __restrict__ Xb, const u16* __restrict__ Ypb, const u16* __restrict__ Ynb,
    const float* __restrict__ bbp, const float* __restrict__ bbn,
    float* __restrict__ M, u64* __restrict__ Kmask)
{
  __shared__ u16 Ah[2][256 * 32];
  __shared__ u16 Bh[2][256 * 32];
  __shared__ float red[8];

  const int tid  = threadIdx.x;

  // T1: XCD-bijective swizzle (512 blocks, 512 % 8 == 0)
  const unsigned lid = blockIdx.x + (blockIdx.y << 4) + (blockIdx.z << 8);
  const unsigned swz = (lid & 7) * 64 + (lid >> 3);
  const int bx = swz & 15, by = (swz >> 4) & 15, side = (int)(swz >> 8);

  const u16* Yb = side ? Ynb : Ypb;
  const float* bbv = side ? bbn : bbp;

  const int lane = tid & 63;
  const int wave = tid >> 6;          // 0..7
  const int wm = wave >> 2, wn = wave & 3;   // 2 x 4
  const int l15 = lane & 15, lhi = lane >> 4;

  const int rf = bx * 256;            // x rows
  const int cf = by * 256;            // y rows (cols of S)
  const int til = by * 4 + wn;

  // staging: 1024 chunk-ids per array (256 rows x 4 chunks of 16B); thread
  // covers cid = tid and tid+512. LDS dest linear; source pre-swizzled with
  // s(r) = (r>>1)&3 (row stride 64B -> same bank math as the 128 tile).
  const int r0  = tid >> 2;
  const int r1  = 128 + (tid >> 2);
  const int pc  = tid & 3;
  const int gc0 = (pc ^ ((r0 >> 1) & 3)) * 8;
  const int gc1 = (pc ^ ((r1 >> 1) & 3)) * 8;

  const u16* xa0 = Xb + (size_t)(rf + r0) * DIM + gc0;
  const u16* xa1 = Xb + (size_t)(rf + r1) * DIM + gc1;
  const u16* ya0 = Yb + (size_t)(cf + r0) * DIM + gc0;
  const u16* ya1 = Yb + (size_t)(cf + r1) * DIM + gc1;

  f32x4 acc[8][4] = {};

#define STAGE(KS, BUF)                                                 \
  do {                                                                 \
    gload_lds16(xa0 + (KS) * 32, Ah[BUF] + r0 * 32 + pc * 8);          \
    gload_lds16(ya0 + (KS) * 32, Bh[BUF] + r0 * 32 + pc * 8);          \
    gload_lds16(xa1 + (KS) * 32, Ah[BUF] + r1 * 32 + pc * 8);          \
    gload_lds16(ya1 + (KS) * 32, Bh[BUF] + r1 * 32 + pc * 8);          \
  } while (0)

  STAGE(0, 0);

  #pragma unroll
  for (int ks = 0; ks < 8; ++ks) {
    const int cur = ks & 1;
    __builtin_amdgcn_s_barrier();          // all waves done reading buf cur^1
    if (ks < 7) {
      STAGE(ks + 1, cur ^ 1);              // prefetch next step into freed buffer
      asm volatile("s_waitcnt vmcnt(4)" ::: "memory");  // wait only for stage(ks)
    } else {
      asm volatile("s_waitcnt vmcnt(0)" ::: "memory");
    }
    __builtin_amdgcn_sched_barrier(0);

    bf16x8 a[8], b[4];
    #pragma unroll
    for (int mi = 0; mi < 8; ++mi) {
      int R = wm * 128 + mi * 16 + l15;
      a[mi] = *reinterpret_cast<const bf16x8*>(Ah[cur] + R * 32 + ((lhi ^ ((R >> 1) & 3)) * 8));
    }
    #pragma unroll
    for (int ni = 0; ni < 4; ++ni) {
      int R = wn * 64 + ni * 16 + l15;
      b[ni] = *reinterpret_cast<const bf16x8*>(Bh[cur] + R * 32 + ((lhi ^ ((R >> 1) & 3)) * 8));
    }
    #pragma unroll
    for (int mi = 0; mi < 8; ++mi)
      #pragma unroll
      for (int ni = 0; ni < 4; ++ni)
        acc[mi][ni] = __builtin_amdgcn_mfma_f32_16x16x32_bf16(a[mi], b[ni], acc[mi][ni], 0, 0, 0);
  }
#undef STAGE

  // ---- epilogue: scalesq (512 threads), then mask/ballot emission ----
  float sq = 0.f;
  #pragma unroll
  for (int q = 0; q < 2; ++q) {
    f32x4 pa = *reinterpret_cast<const f32x4*>(bbp + (q * 512 + tid) * 4);
    f32x4 nb = *reinterpret_cast<const f32x4*>(bbn + (q * 512 + tid) * 4);
    sq += pa[0] + pa[1] + pa[2] + pa[3] + nb[0] + nb[1] + nb[2] + nb[3];
  }
  const float scalesq = blk_sum8(sq, red) * (1.0f / (2.0f * NPTS * DIM)) + 1e-8f;
  const float thrP = 30.0f * scalesq * 0.2f + 2.5f * scalesq + 0.5f;

  float bbc[4];
  #pragma unroll
  for (int ni = 0; ni < 4; ++ni) bbc[ni] = bbv[cf + wn * 64 + ni * 16 + l15];

  #pragma unroll
  for (int mi = 0; mi < 8; ++mi)
    #pragma unroll
    for (int r = 0; r < 4; ++r) {
      float uv[4];
      float mx = -3.0e38f;
      #pragma unroll
      for (int ni = 0; ni < 4; ++ni) {
        uv[ni] = 2.0f * acc[mi][ni][r] - bbc[ni];
        mx = fmaxf(mx, uv[ni]);
      }
      #pragma unroll
      for (int off = 1; off < 16; off <<= 1) mx = fmaxf(mx, __shfl_xor(mx, off));
      const float cut = mx - thrP;

      u64 bal[4];
      #pragma unroll
      for (int ni = 0; ni < 4; ++ni) bal[ni] = __ballot(uv[ni] > cut);

      u64 mask = 0;
      #pragma unroll
      for (int ni = 0; ni < 4; ++ni)
        mask |= ((bal[ni] >> (lhi * 16)) & 0xFFFFull) << (ni * 16);

      const int rowG = rf + wm * 128 + mi * 16 + lhi * 4 + r;
      if (l15 == 0) {
        // transposed layout [side][row][til]: row_kernel lane t reads tile t coalesced
        Kmask[((size_t)side * NPTS + rowG) * TIL + til] = mask;
        M[((size_t)side * NPTS + rowG) * TIL + til] = mx;
      }
    }
}

// ---------- K3: wave-per-row; PARALLEL mask harvest (lane t owns tile t) ----------
__global__ __launch_bounds__(256) void row_kernel(
    const float* __restrict__ M, const u64* __restrict__ Kmask,
    const float* __restrict__ bbp, const float* __restrict__ bbn,
    const float* __restrict__ x,
    const float* __restrict__ ypos, const float* __restrict__ yneg,
    float* __restrict__ parts, float* __restrict__ Vout)
{
  __shared__ unsigned cl[4][2][WCAND];
  __shared__ float red[4];

  const int tid  = threadIdx.x;
  const int lane = tid & 63;
  const int w    = tid >> 6;
  const int row  = blockIdx.x * 4 + w;

  // issue all harvest loads up front (coalesced, both sides in flight)
  float Mv[2]; u64 km[2];
  #pragma unroll
  for (int side = 0; side < 2; ++side) {
    Mv[side] = M[((size_t)side * NPTS + row) * TIL + lane];
    km[side] = Kmask[((size_t)side * NPTS + row) * TIL + lane];
  }
  const f32x4 xv = *reinterpret_cast<const f32x4*>(x + (size_t)row * DIM + lane * 4);

  const float scalesq = block_scalesq(bbp, bbn, red, tid);  // overlaps the loads above
  const float L2E = 1.4426950408889634f;
  const float c0 = L2E / (scalesq * 0.02f);
  const float c1 = L2E / (scalesq * 0.05f);
  const float c2 = L2E / (scalesq * 0.2f);
  const float thrP = 30.0f * scalesq * 0.2f + 2.5f * scalesq + 0.5f;

  // parallel harvest: lane t owns tile t; prefix-sum compaction
  int ncs[2];
  #pragma unroll
  for (int side = 0; side < 2; ++side) {
    float g = Mv[side];
    #pragma unroll
    for (int off = 32; off; off >>= 1) g = fmaxf(g, __shfl_xor(g, off));
    u64 mk = (Mv[side] > g - thrP) ? km[side] : 0ull;
    int mycnt = __popcll(mk);
    int pfx = mycnt;
    #pragma unroll
    for (int off = 1; off < 64; off <<= 1) {
      int t = __shfl_up(pfx, off);
      if (lane >= off) pfx += t;
    }
    int base = pfx - mycnt;
    int nc = __shfl(pfx, 63);
    u64 b = mk;
    int s = base;
    while (b) {
      int bit = __ffsll((long long)b) - 1;
      b &= b - 1;
      if (s < WCAND) cl[w][side][s] = lane * 64 + bit;
      ++s;
    }
    ncs[side] = nc < WCAND ? nc : WCAND;
  }
  // same-wave LDS write->read; DS pipe in-order per wave

  f32x4 V0 = {0,0,0,0}, V1 = {0,0,0,0}, V2 = {0,0,0,0};

  for (int side = 0; side < 2; ++side) {
    const float* bb = side ? bbn : bbp;
    const float* y  = side ? yneg : ypos;
    const float sgn = side ? -1.f : 1.f;
    const int nc = ncs[side];

    // chunks of 8 candidates, y rows register-resident, online-rescaled softmax
    float me = -3.0e38f, p0 = 0.f, p1 = 0.f, p2 = 0.f;
    f32x4 A0 = {0,0,0,0}, A1 = {0,0,0,0}, A2 = {0,0,0,0};
    for (int bs = 0; bs < nc; bs += 8) {
      const int rem = nc - bs;
      int jq[8];
      f32x4 yv[8];
      float dq[8], uq[8];
      #pragma unroll
      for (int q = 0; q < 8; ++q) {
        int idx = (q < rem) ? bs + q : bs;
        jq[q] = (int)cl[w][side][idx];
        yv[q] = *reinterpret_cast<const f32x4*>(y + (size_t)jq[q] * DIM + lane * 4);
      }
      #pragma unroll
      for (int q = 0; q < 8; ++q)
        dq[q] = xv[0]*yv[q][0] + xv[1]*yv[q][1] + xv[2]*yv[q][2] + xv[3]*yv[q][3];
      #pragma unroll
      for (int off = 32; off; off >>= 1)
        #pragma unroll
        for (int q = 0; q < 8; ++q) dq[q] += __shfl_xor(dq[q], off);
      #pragma unroll
      for (int q = 0; q < 8; ++q)
        uq[q] = (q < rem) ? 2.0f * dq[q] - bb[jq[q]] : -3.0e38f;

      float cm = uq[0];
      #pragma unroll
      for (int q = 1; q < 8; ++q) cm = fmaxf(cm, uq[q]);
      float nm = fmaxf(me, cm);
      float s0 = exp2fast((me - nm) * c0);
      float s1 = exp2fast((me - nm) * c1);
      float s2 = exp2fast((me - nm) * c2);
      p0 *= s0; p1 *= s1; p2 *= s2;
      A0 *= s0; A1 *= s1; A2 *= s2;
      #pragma unroll
      for (int q = 0; q < 8; ++q) {
        float du = uq[q] - nm;
        float e0 = exp2fast(du * c0);
        float e1 = exp2fast(du * c1);
        float e2 = exp2fast(du * c2);
        p0 += e0; p1 += e1; p2 += e2;
        A0 += e0 * yv[q]; A1 += e1 * yv[q]; A2 += e2 * yv[q];
      }
      me = nm;
    }
    V0 += (sgn / p0) * A0;
    V1 += (sgn / p1) * A1;
    V2 += (sgn / p2) * A2;
  }

  f32x4 vr = (V0 + V1 + V2) * (1.0f / 3.0f);
  *reinterpret_cast<f32x4*>(Vout + (size_t)row * DIM + lane * 4) = vr;

  float s0 = V0[0]*V0[0] + V0[1]*V0[1] + V0[2]*V0[2] + V0[3]*V0[3];
  float s1 = V1[0]*V1[0] + V1[1]*V1[1] + V1[2]*V1[2] + V1[3]*V1[3];
  float s2 = V2[0]*V2[0] + V2[1]*V2[1] + V2[2]*V2[2] + V2[3]*V2[3];
  float sr = vr[0]*vr[0] + vr[1]*vr[1] + vr[2]*vr[2] + vr[3]*vr[3];
  #pragma unroll
  for (int off = 32; off; off >>= 1) {
    s0 += __shfl_xor(s0, off);
    s1 += __shfl_xor(s1, off);
    s2 += __shfl_xor(s2, off);
    sr += __shfl_xor(sr, off);
  }
  if (lane == 0) {
    parts[row]            = sr;
    parts[NPTS + row]     = s0;
    parts[2 * NPTS + row] = s1;
    parts[3 * NPTS + row] = s2;
  }
}

// ---------- K4: fused reduce + finalize + V scale ----------
__global__ __launch_bounds__(256) void final_kernel(
    const float* __restrict__ parts, float* __restrict__ out)
{
  __shared__ float red[4];
  const int tid = threadIdx.x;

  float s = 0.f;
  for (int k = tid; k < NPTS; k += 256) s += parts[k];
  float raw = blk_sum4(s, red) * (1.0f / NPTS);
  float lam2 = raw * (1.0f / DIM) + 1e-8f;
  float lam  = sqrtf(lam2);
  float inv  = 1.0f / lam;

  int idx = blockIdx.x * 256 + tid;
  out[7 + idx] *= inv;

  if (blockIdx.x == 0) {
    #pragma unroll
    for (int a = 1; a <= 3; ++a) {
      float t = 0.f;
      for (int k = tid; k < NPTS; k += 256) t += parts[a * NPTS + k];
      t = blk_sum4(t, red);
      if (tid == 0) out[3 + a] = t * (1.0f / NPTS);
    }
    if (tid == 0) {
      float drift = raw / lam2;
      out[0] = drift * (1.0f / DIM);
      out[1] = drift;
      out[2] = raw;
      out[3] = lam;
    }
  }
}

extern "C" void kernel_launch(void* const* d_in, const int* in_sizes, int n_in,
                              void* d_out, int out_size, void* d_ws, size_t ws_size,
                              hipStream_t stream)
{
  (void)in_sizes; (void)n_in; (void)out_size; (void)ws_size;
  const float* x    = (const float*)d_in[0];
  const float* ypos = (const float*)d_in[1];
  const float* yneg = (const float*)d_in[2];
  float* out = (float*)d_out;
  char* ws = (char*)d_ws;

  // ws layout (M/Kmask fully rewritten each launch; no zeroing needed):
  // bbp 16K | bbn 16K | parts 64K | M 2M | Kmask 4M | xb/ypb/ynb 6M
  float* bbp   = (float*)ws;
  float* bbn   = (float*)(ws + 16384);
  float* parts = (float*)(ws + 32768);
  float* M     = (float*)(ws + 98304);
  u64*   Kmask = (u64*)(ws + 98304 + 2097152);
  u16* xb  = (u16*)(ws + 98304 + 2097152 + 4194304);
  u16* ypb = xb + (size_t)NPTS * DIM;
  u16* ynb = xb + 2 * (size_t)NPTS * DIM;

  split3_kernel<<<dim3(NPTS / 4, 3), 256, 0, stream>>>(x, ypos, yneg, xb, ypb, ynb, bbp, bbn);
  gemm_kernel<<<dim3(16, 16, 2), 512, 0, stream>>>(xb, ypb, ynb, bbp, bbn, M, Kmask);
  row_kernel<<<NPTS / 4, 256, 0, stream>>>(M, Kmask, bbp, bbn, x, ypos, yneg,
                                           parts, out + 7);
  final_kernel<<<NPTS, 256, 0, stream>>>(parts, out);
}

// Round 18
// 101.399 us; speedup vs baseline: 2.0164x; 2.0164x over previous
//
#include <hip/hip_runtime.h>

#define NPTS 4096
#define DIM  256
#define TIL  64       // number of 64-wide col tiles
#define WCAND 32      // per-row candidate cap in row_kernel

typedef unsigned short u16;
typedef unsigned long long u64;
typedef __attribute__((ext_vector_type(8))) short bf16x8;
typedef __attribute__((ext_vector_type(4))) float f32x4;
typedef __attribute__((ext_vector_type(4))) unsigned short u16x4;

__device__ __forceinline__ float exp2fast(float x) {
  float r;
  asm("v_exp_f32 %0, %1" : "=v"(r) : "v"(x));
  return r;
}

__device__ __forceinline__ void gload_lds16(const void* g, void* l) {
  __builtin_amdgcn_global_load_lds((const __attribute__((address_space(1))) void*)g,
                                   (__attribute__((address_space(3))) void*)l, 16, 0, 0);
}

__device__ __forceinline__ float blk_sum4(float v, float* sh) {
  #pragma unroll
  for (int off = 32; off; off >>= 1) v += __shfl_down(v, off);
  int lane = threadIdx.x & 63, w = threadIdx.x >> 6;
  __syncthreads();
  if (lane == 0) sh[w] = v;
  __syncthreads();
  return sh[0] + sh[1] + sh[2] + sh[3];
}

// per-block redundant scalesq: reduces bbp+bbn (8192 floats, L2-hot)
__device__ __forceinline__ float block_scalesq(
    const float* __restrict__ bbp, const float* __restrict__ bbn, float* red, int tid) {
  float s = 0.f;
  #pragma unroll
  for (int q = 0; q < 4; ++q) {
    f32x4 a = *reinterpret_cast<const f32x4*>(bbp + (q * 256 + tid) * 4);
    f32x4 b = *reinterpret_cast<const f32x4*>(bbn + (q * 256 + tid) * 4);
    s += a[0] + a[1] + a[2] + a[3] + b[0] + b[1] + b[2] + b[3];
  }
  float tot = blk_sum4(s, red);
  return tot * (1.0f / (2.0f * NPTS * DIM)) + 1e-8f;
}

// ---------- K1: bf16 round + row sumsq for all three inputs ----------
__global__ __launch_bounds__(256) void split3_kernel(
    const float* __restrict__ x, const float* __restrict__ yp, const float* __restrict__ yn,
    u16* __restrict__ xb, u16* __restrict__ ypb, u16* __restrict__ ynb,
    float* __restrict__ bbp, float* __restrict__ bbn)
{
  const float* src; u16* dst; float* bb;
  if      (blockIdx.y == 0) { src = x;  dst = xb;  bb = nullptr; }
  else if (blockIdx.y == 1) { src = yp; dst = ypb; bb = bbp; }
  else                      { src = yn; dst = ynb; bb = bbn; }

  int lane = threadIdx.x & 63;
  int wave = threadIdx.x >> 6;
  int row  = blockIdx.x * 4 + wave;
  const float4 v = *reinterpret_cast<const float4*>(src + (size_t)row * DIM + lane * 4);
  float xs[4] = {v.x, v.y, v.z, v.w};
  u16x4 h;
  float ss = 0.f;
  #pragma unroll
  for (int e = 0; e < 4; ++e) {
    unsigned b = __float_as_uint(xs[e]);
    h[e] = (u16)((b + 0x7fffu + ((b >> 16) & 1u)) >> 16);   // bf16 RTNE
    ss += xs[e] * xs[e];
  }
  *reinterpret_cast<u16x4*>(dst + (size_t)row * DIM + lane * 4) = h;
  if (bb) {
    #pragma unroll
    for (int off = 32; off; off >>= 1) ss += __shfl_down(ss, off);
    if (lane == 0) bb[row] = ss;
  }
}

// ---------- K2: side-merged bf16 GEMM 128x128x2sides, 2-buf, mask epilogue ----------
// A panel staged once, consumed by both P and N B-panels: 32 MFMA/wave/step.
// per step: barrier -> STAGE(ks+1) [6 loads] -> vmcnt(6) -> ds_read(cur) -> MFMA.
__global__ __launch_bounds__(256) void gemm_kernel(
    const u16* __restrict__ Xb, const u16* __restrict__ Ypb, const u16* __restrict__ Ynb,
    const float* __restrict__ bbp, const float* __restrict__ bbn,
    float* __restrict__ M, u64* __restrict__ Kmask)
{
  __shared__ u16 Ah[2][128 * 32];
  __shared__ u16 Bp[2][128 * 32];
  __shared__ u16 Bn[2][128 * 32];
  __shared__ float red[4];

  const int tid  = threadIdx.x;

  // T1: XCD-bijective swizzle (1024 blocks, 1024 % 8 == 0)
  const unsigned lid = blockIdx.x + (blockIdx.y << 5);
  const unsigned swz = (lid & 7) * 128 + (lid >> 3);
  const int bx = swz & 31, by = (int)(swz >> 5);

  const int lane = tid & 63;
  const int wave = tid >> 6;
  const int wm = wave >> 1, wn = wave & 1;
  const int l15 = lane & 15, lhi = lane >> 4;

  const int rf = bx * 128;           // x rows
  const int cf = by * 128;           // y rows (cols of S)
  const int til = by * 2 + wn;

  // staging coords: cid = tid (+256); (row, phys chunk) = (cid>>2, cid&3)
  // LDS dest linear; global source chunk pre-swizzled with s(r) = (r>>1)&3.
  const int r0  = tid >> 2;
  const int r1  = 64 + (tid >> 2);
  const int pc  = tid & 3;
  const int gc0 = (pc ^ ((r0 >> 1) & 3)) * 8;
  const int gc1 = (pc ^ ((r1 >> 1) & 3)) * 8;

  // base addresses; per-step K offset becomes an immediate after full unroll
  const u16* xa0 = Xb  + (size_t)(rf + r0) * DIM + gc0;
  const u16* xa1 = Xb  + (size_t)(rf + r1) * DIM + gc1;
  const u16* yp0 = Ypb + (size_t)(cf + r0) * DIM + gc0;
  const u16* yp1 = Ypb + (size_t)(cf + r1) * DIM + gc1;
  const u16* yn0 = Ynb + (size_t)(cf + r0) * DIM + gc0;
  const u16* yn1 = Ynb + (size_t)(cf + r1) * DIM + gc1;

  f32x4 accP[4][4] = {};
  f32x4 accN[4][4] = {};

#define STAGE(KS, BUF)                                                 \
  do {                                                                 \
    gload_lds16(xa0 + (KS) * 32, Ah[BUF] + r0 * 32 + pc * 8);          \
    gload_lds16(yp0 + (KS) * 32, Bp[BUF] + r0 * 32 + pc * 8);          \
    gload_lds16(yn0 + (KS) * 32, Bn[BUF] + r0 * 32 + pc * 8);          \
    gload_lds16(xa1 + (KS) * 32, Ah[BUF] + r1 * 32 + pc * 8);          \
    gload_lds16(yp1 + (KS) * 32, Bp[BUF] + r1 * 32 + pc * 8);          \
    gload_lds16(yn1 + (KS) * 32, Bn[BUF] + r1 * 32 + pc * 8);          \
  } while (0)

  STAGE(0, 0);

  #pragma unroll
  for (int ks = 0; ks < 8; ++ks) {
    const int cur = ks & 1;
    __builtin_amdgcn_s_barrier();          // all waves done reading buf cur^1
    if (ks < 7) {
      STAGE(ks + 1, cur ^ 1);              // prefetch next step into freed buffer
      asm volatile("s_waitcnt vmcnt(6)" ::: "memory");  // wait only for stage(ks)'s 6
    } else {
      asm volatile("s_waitcnt vmcnt(0)" ::: "memory");
    }
    __builtin_amdgcn_sched_barrier(0);

    bf16x8 a[4], bp[4], bn[4];
    #pragma unroll
    for (int mi = 0; mi < 4; ++mi) {
      int R = wm * 64 + mi * 16 + l15;
      a[mi] = *reinterpret_cast<const bf16x8*>(Ah[cur] + R * 32 + ((lhi ^ ((R >> 1) & 3)) * 8));
    }
    #pragma unroll
    for (int ni = 0; ni < 4; ++ni) {
      int R = wn * 64 + ni * 16 + l15;
      int off = R * 32 + ((lhi ^ ((R >> 1) & 3)) * 8);
      bp[ni] = *reinterpret_cast<const bf16x8*>(Bp[cur] + off);
      bn[ni] = *reinterpret_cast<const bf16x8*>(Bn[cur] + off);
    }
    #pragma unroll
    for (int mi = 0; mi < 4; ++mi)
      #pragma unroll
      for (int ni = 0; ni < 4; ++ni) {
        accP[mi][ni] = __builtin_amdgcn_mfma_f32_16x16x32_bf16(a[mi], bp[ni], accP[mi][ni], 0, 0, 0);
        accN[mi][ni] = __builtin_amdgcn_mfma_f32_16x16x32_bf16(a[mi], bn[ni], accN[mi][ni], 0, 0, 0);
      }
  }
#undef STAGE

  // ---- epilogue: scalesq, then mask/ballot emission (compile-time side) ----
  const float scalesq = block_scalesq(bbp, bbn, red, tid);
  const float thrP = 30.0f * scalesq * 0.2f + 2.5f * scalesq + 0.5f;

#define EMIT(ACC, BBV, SIDE)                                                     \
  do {                                                                           \
    float bbc[4];                                                                \
    _Pragma("unroll")                                                            \
    for (int ni = 0; ni < 4; ++ni) bbc[ni] = (BBV)[cf + wn * 64 + ni * 16 + l15];\
    _Pragma("unroll")                                                            \
    for (int mi = 0; mi < 4; ++mi)                                               \
      _Pragma("unroll")                                                          \
      for (int r = 0; r < 4; ++r) {                                              \
        float uv[4];                                                             \
        float mx = -3.0e38f;                                                     \
        _Pragma("unroll")                                                        \
        for (int ni = 0; ni < 4; ++ni) {                                         \
          uv[ni] = 2.0f * (ACC)[mi][ni][r] - bbc[ni];                            \
          mx = fmaxf(mx, uv[ni]);                                                \
        }                                                                        \
        _Pragma("unroll")                                                        \
        for (int off = 1; off < 16; off <<= 1) mx = fmaxf(mx, __shfl_xor(mx, off)); \
        const float cut = mx - thrP;                                             \
        u64 mask = 0;                                                            \
        _Pragma("unroll")                                                        \
        for (int ni = 0; ni < 4; ++ni) {                                         \
          u64 bal = __ballot(uv[ni] > cut);                                      \
          mask |= ((bal >> (lhi * 16)) & 0xFFFFull) << (ni * 16);                \
        }                                                                        \
        const int rowG = rf + wm * 64 + mi * 16 + lhi * 4 + r;                   \
        if (l15 == 0) {                                                          \
          Kmask[((size_t)(SIDE) * NPTS + rowG) * TIL + til] = mask;              \
          M[((size_t)(SIDE) * NPTS + rowG) * TIL + til] = mx;                    \
        }                                                                        \
      }                                                                          \
  } while (0)

  EMIT(accP, bbp, 0);
  EMIT(accN, bbn, 1);
#undef EMIT
}

// ---------- K3: wave-per-row; PARALLEL mask harvest (lane t owns tile t) ----------
__global__ __launch_bounds__(256) void row_kernel(
    const float* __restrict__ M, const u64* __restrict__ Kmask,
    const float* __restrict__ bbp, const float* __restrict__ bbn,
    const float* __restrict__ x,
    const float* __restrict__ ypos, const float* __restrict__ yneg,
    float* __restrict__ parts, float* __restrict__ Vout)
{
  __shared__ unsigned cl[4][2][WCAND];
  __shared__ float red[4];

  const int tid  = threadIdx.x;
  const int lane = tid & 63;
  const int w    = tid >> 6;
  const int row  = blockIdx.x * 4 + w;

  // issue all harvest loads up front (coalesced, both sides in flight)
  float Mv[2]; u64 km[2];
  #pragma unroll
  for (int side = 0; side < 2; ++side) {
    Mv[side] = M[((size_t)side * NPTS + row) * TIL + lane];
    km[side] = Kmask[((size_t)side * NPTS + row) * TIL + lane];
  }
  const f32x4 xv = *reinterpret_cast<const f32x4*>(x + (size_t)row * DIM + lane * 4);

  const float scalesq = block_scalesq(bbp, bbn, red, tid);  // overlaps the loads above
  const float L2E = 1.4426950408889634f;
  const float c0 = L2E / (scalesq * 0.02f);
  const float c1 = L2E / (scalesq * 0.05f);
  const float c2 = L2E / (scalesq * 0.2f);
  const float thrP = 30.0f * scalesq * 0.2f + 2.5f * scalesq + 0.5f;

  // parallel harvest: lane t owns tile t; prefix-sum compaction
  int ncs[2];
  #pragma unroll
  for (int side = 0; side < 2; ++side) {
    float g = Mv[side];
    #pragma unroll
    for (int off = 32; off; off >>= 1) g = fmaxf(g, __shfl_xor(g, off));
    u64 mk = (Mv[side] > g - thrP) ? km[side] : 0ull;
    int mycnt = __popcll(mk);
    int pfx = mycnt;
    #pragma unroll
    for (int off = 1; off < 64; off <<= 1) {
      int t = __shfl_up(pfx, off);
      if (lane >= off) pfx += t;
    }
    int base = pfx - mycnt;
    int nc = __shfl(pfx, 63);
    u64 b = mk;
    int s = base;
    while (b) {
      int bit = __ffsll((long long)b) - 1;
      b &= b - 1;
      if (s < WCAND) cl[w][side][s] = lane * 64 + bit;
      ++s;
    }
    ncs[side] = nc < WCAND ? nc : WCAND;
  }
  // same-wave LDS write->read; DS pipe in-order per wave

  f32x4 V0 = {0,0,0,0}, V1 = {0,0,0,0}, V2 = {0,0,0,0};

  for (int side = 0; side < 2; ++side) {
    const float* bb = side ? bbn : bbp;
    const float* y  = side ? yneg : ypos;
    const float sgn = side ? -1.f : 1.f;
    const int nc = ncs[side];

    // chunks of 8 candidates, y rows register-resident, online-rescaled softmax
    float me = -3.0e38f, p0 = 0.f, p1 = 0.f, p2 = 0.f;
    f32x4 A0 = {0,0,0,0}, A1 = {0,0,0,0}, A2 = {0,0,0,0};
    for (int bs = 0; bs < nc; bs += 8) {
      const int rem = nc - bs;
      int jq[8];
      f32x4 yv[8];
      float dq[8], uq[8];
      #pragma unroll
      for (int q = 0; q < 8; ++q) {
        int idx = (q < rem) ? bs + q : bs;
        jq[q] = (int)cl[w][side][idx];
        yv[q] = *reinterpret_cast<const f32x4*>(y + (size_t)jq[q] * DIM + lane * 4);
      }
      #pragma unroll
      for (int q = 0; q < 8; ++q)
        dq[q] = xv[0]*yv[q][0] + xv[1]*yv[q][1] + xv[2]*yv[q][2] + xv[3]*yv[q][3];
      #pragma unroll
      for (int off = 32; off; off >>= 1)
        #pragma unroll
        for (int q = 0; q < 8; ++q) dq[q] += __shfl_xor(dq[q], off);
      #pragma unroll
      for (int q = 0; q < 8; ++q)
        uq[q] = (q < rem) ? 2.0f * dq[q] - bb[jq[q]] : -3.0e38f;

      float cm = uq[0];
      #pragma unroll
      for (int q = 1; q < 8; ++q) cm = fmaxf(cm, uq[q]);
      float nm = fmaxf(me, cm);
      float s0 = exp2fast((me - nm) * c0);
      float s1 = exp2fast((me - nm) * c1);
      float s2 = exp2fast((me - nm) * c2);
      p0 *= s0; p1 *= s1; p2 *= s2;
      A0 *= s0; A1 *= s1; A2 *= s2;
      #pragma unroll
      for (int q = 0; q < 8; ++q) {
        float du = uq[q] - nm;
        float e0 = exp2fast(du * c0);
        float e1 = exp2fast(du * c1);
        float e2 = exp2fast(du * c2);
        p0 += e0; p1 += e1; p2 += e2;
        A0 += e0 * yv[q]; A1 += e1 * yv[q]; A2 += e2 * yv[q];
      }
      me = nm;
    }
    V0 += (sgn / p0) * A0;
    V1 += (sgn / p1) * A1;
    V2 += (sgn / p2) * A2;
  }

  f32x4 vr = (V0 + V1 + V2) * (1.0f / 3.0f);
  *reinterpret_cast<f32x4*>(Vout + (size_t)row * DIM + lane * 4) = vr;

  float s0 = V0[0]*V0[0] + V0[1]*V0[1] + V0[2]*V0[2] + V0[3]*V0[3];
  float s1 = V1[0]*V1[0] + V1[1]*V1[1] + V1[2]*V1[2] + V1[3]*V1[3];
  float s2 = V2[0]*V2[0] + V2[1]*V2[1] + V2[2]*V2[2] + V2[3]*V2[3];
  float sr = vr[0]*vr[0] + vr[1]*vr[1] + vr[2]*vr[2] + vr[3]*vr[3];
  #pragma unroll
  for (int off = 32; off; off >>= 1) {
    s0 += __shfl_xor(s0, off);
    s1 += __shfl_xor(s1, off);
    s2 += __shfl_xor(s2, off);
    sr += __shfl_xor(sr, off);
  }
  if (lane == 0) {
    parts[row]            = sr;
    parts[NPTS + row]     = s0;
    parts[2 * NPTS + row] = s1;
    parts[3 * NPTS + row] = s2;
  }
}

// ---------- K4: fused reduce + finalize + V scale ----------
__global__ __launch_bounds__(256) void final_kernel(
    const float* __restrict__ parts, float* __restrict__ out)
{
  __shared__ float red[4];
  const int tid = threadIdx.x;

  float s = 0.f;
  for (int k = tid; k < NPTS; k += 256) s += parts[k];
  float raw = blk_sum4(s, red) * (1.0f / NPTS);
  float lam2 = raw * (1.0f / DIM) + 1e-8f;
  float lam  = sqrtf(lam2);
  float inv  = 1.0f / lam;

  int idx = blockIdx.x * 256 + tid;
  out[7 + idx] *= inv;

  if (blockIdx.x == 0) {
    #pragma unroll
    for (int a = 1; a <= 3; ++a) {
      float t = 0.f;
      for (int k = tid; k < NPTS; k += 256) t += parts[a * NPTS + k];
      t = blk_sum4(t, red);
      if (tid == 0) out[3 + a] = t * (1.0f / NPTS);
    }
    if (tid == 0) {
      float drift = raw / lam2;
      out[0] = drift * (1.0f / DIM);
      out[1] = drift;
      out[2] = raw;
      out[3] = lam;
    }
  }
}

extern "C" void kernel_launch(void* const* d_in, const int* in_sizes, int n_in,
                              void* d_out, int out_size, void* d_ws, size_t ws_size,
                              hipStream_t stream)
{
  (void)in_sizes; (void)n_in; (void)out_size; (void)ws_size;
  const float* x    = (const float*)d_in[0];
  const float* ypos = (const float*)d_in[1];
  const float* yneg = (const float*)d_in[2];
  float* out = (float*)d_out;
  char* ws = (char*)d_ws;

  // ws layout (M/Kmask fully rewritten each launch; no zeroing needed):
  // bbp 16K | bbn 16K | parts 64K | M 2M | Kmask 4M | xb/ypb/ynb 6M
  float* bbp   = (float*)ws;
  float* bbn   = (float*)(ws + 16384);
  float* parts = (float*)(ws + 32768);
  float* M     = (float*)(ws + 98304);
  u64*   Kmask = (u64*)(ws + 98304 + 2097152);
  u16* xb  = (u16*)(ws + 98304 + 2097152 + 4194304);
  u16* ypb = xb + (size_t)NPTS * DIM;
  u16* ynb = xb + 2 * (size_t)NPTS * DIM;

  split3_kernel<<<dim3(NPTS / 4, 3), 256, 0, stream>>>(x, ypos, yneg, xb, ypb, ynb, bbp, bbn);
  gemm_kernel<<<dim3(32, 32), 256, 0, stream>>>(xb, ypb, ynb, bbp, bbn, M, Kmask);
  row_kernel<<<NPTS / 4, 256, 0, stream>>>(M, Kmask, bbp, bbn, x, ypos, yneg,
                                           parts, out + 7);
  final_kernel<<<NPTS, 256, 0, stream>>>(parts, out);
}

// Round 20
// 77.407 us; speedup vs baseline: 2.6414x; 1.3100x over previous
//
#include <hip/hip_runtime.h>

#define NPTS 4096
#define DIM  256
#define TIL  64       // number of 64-wide col tiles
#define WCAND 32      // per-row candidate cap in row_kernel

typedef unsigned short u16;
typedef unsigned long long u64;
typedef __attribute__((ext_vector_type(8))) short bf16x8;
typedef __attribute__((ext_vector_type(4))) float f32x4;
typedef __attribute__((ext_vector_type(4))) unsigned short u16x4;

__device__ __forceinline__ float exp2fast(float x) {
  float r;
  asm("v_exp_f32 %0, %1" : "=v"(r) : "v"(x));
  return r;
}

__device__ __forceinline__ void gload_lds16(const void* g, void* l) {
  __builtin_amdgcn_global_load_lds((const __attribute__((address_space(1))) void*)g,
                                   (__attribute__((address_space(3))) void*)l, 16, 0, 0);
}

__device__ __forceinline__ float blk_sum4(float v, float* sh) {
  #pragma unroll
  for (int off = 32; off; off >>= 1) v += __shfl_down(v, off);
  int lane = threadIdx.x & 63, w = threadIdx.x >> 6;
  __syncthreads();
  if (lane == 0) sh[w] = v;
  __syncthreads();
  return sh[0] + sh[1] + sh[2] + sh[3];
}

// per-block redundant scalesq: reduces bbp+bbn (8192 floats, L2-hot)
__device__ __forceinline__ float block_scalesq(
    const float* __restrict__ bbp, const float* __restrict__ bbn, float* red, int tid) {
  float s = 0.f;
  #pragma unroll
  for (int q = 0; q < 4; ++q) {
    f32x4 a = *reinterpret_cast<const f32x4*>(bbp + (q * 256 + tid) * 4);
    f32x4 b = *reinterpret_cast<const f32x4*>(bbn + (q * 256 + tid) * 4);
    s += a[0] + a[1] + a[2] + a[3] + b[0] + b[1] + b[2] + b[3];
  }
  float tot = blk_sum4(s, red);
  return tot * (1.0f / (2.0f * NPTS * DIM)) + 1e-8f;
}

// ---------- K1: bf16 round + row sumsq for all three inputs ----------
__global__ __launch_bounds__(256) void split3_kernel(
    const float* __restrict__ x, const float* __restrict__ yp, const float* __restrict__ yn,
    u16* __restrict__ xb, u16* __restrict__ ypb, u16* __restrict__ ynb,
    float* __restrict__ bbp, float* __restrict__ bbn)
{
  const float* src; u16* dst; float* bb;
  if      (blockIdx.y == 0) { src = x;  dst = xb;  bb = nullptr; }
  else if (blockIdx.y == 1) { src = yp; dst = ypb; bb = bbp; }
  else                      { src = yn; dst = ynb; bb = bbn; }

  int lane = threadIdx.x & 63;
  int wave = threadIdx.x >> 6;
  int row  = blockIdx.x * 4 + wave;
  const float4 v = *reinterpret_cast<const float4*>(src + (size_t)row * DIM + lane * 4);
  float xs[4] = {v.x, v.y, v.z, v.w};
  u16x4 h;
  float ss = 0.f;
  #pragma unroll
  for (int e = 0; e < 4; ++e) {
    unsigned b = __float_as_uint(xs[e]);
    h[e] = (u16)((b + 0x7fffu + ((b >> 16) & 1u)) >> 16);   // bf16 RTNE
    ss += xs[e] * xs[e];
  }
  *reinterpret_cast<u16x4*>(dst + (size_t)row * DIM + lane * 4) = h;
  if (bb) {
    #pragma unroll
    for (int off = 32; off; off >>= 1) ss += __shfl_down(ss, off);
    if (lane == 0) bb[row] = ss;
  }
}

// ---------- K2: bf16 GEMM 128x128, 2-buffer dbuf, mask epilogue ----------
// per step: barrier -> STAGE(ks+1) -> vmcnt(4) -> ds_read(cur) -> MFMA.
// After the barrier all waves finished reading buf^1 (WAR safe); vmcnt(4) waits
// only for stage(ks)'s 4 older loads (issued one full step ago -> ~0 stall).
__global__ __launch_bounds__(256, 5) void gemm_kernel(
    const u16* __restrict__ Xb, const u16* __restrict__ Ypb, const u16* __restrict__ Ynb,
    const float* __restrict__ bbp, const float* __restrict__ bbn,
    float* __restrict__ M, u64* __restrict__ Kmask)
{
  __shared__ u16 Ah[2][128 * 32];
  __shared__ u16 Bh[2][128 * 32];
  __shared__ float red[4];

  const int tid  = threadIdx.x;

  // T1: XCD-bijective swizzle (2048 blocks, 2048 % 8 == 0)
  const unsigned lid = blockIdx.x + (blockIdx.y << 5) + (blockIdx.z << 10);
  const unsigned swz = (lid & 7) * 256 + (lid >> 3);
  const int bx = swz & 31, by = (swz >> 5) & 31, side = (int)(swz >> 10);

  const u16* Yb = side ? Ynb : Ypb;
  const float* bbv = side ? bbn : bbp;

  const int lane = tid & 63;
  const int wave = tid >> 6;
  const int wm = wave >> 1, wn = wave & 1;
  const int l15 = lane & 15, lhi = lane >> 4;

  const int rf = bx * 128;           // x rows
  const int cf = by * 128;           // y rows (cols of S)
  const int til = by * 2 + wn;

  // staging coords: cid = tid (+256); (row, phys chunk) = (cid>>2, cid&3)
  // LDS dest linear; global source chunk pre-swizzled with s(r) = (r>>1)&3.
  const int r0  = tid >> 2;
  const int r1  = 64 + (tid >> 2);
  const int pc  = tid & 3;
  const int gc0 = (pc ^ ((r0 >> 1) & 3)) * 8;
  const int gc1 = (pc ^ ((r1 >> 1) & 3)) * 8;

  // base addresses; per-step K offset becomes an immediate after full unroll
  const u16* xa0 = Xb + (size_t)(rf + r0) * DIM + gc0;
  const u16* xa1 = Xb + (size_t)(rf + r1) * DIM + gc1;
  const u16* ya0 = Yb + (size_t)(cf + r0) * DIM + gc0;
  const u16* ya1 = Yb + (size_t)(cf + r1) * DIM + gc1;

  f32x4 acc[4][4] = {};

#define STAGE(KS, BUF)                                                 \
  do {                                                                 \
    gload_lds16(xa0 + (KS) * 32, Ah[BUF] + r0 * 32 + pc * 8);          \
    gload_lds16(ya0 + (KS) * 32, Bh[BUF] + r0 * 32 + pc * 8);          \
    gload_lds16(xa1 + (KS) * 32, Ah[BUF] + r1 * 32 + pc * 8);          \
    gload_lds16(ya1 + (KS) * 32, Bh[BUF] + r1 * 32 + pc * 8);          \
  } while (0)

  STAGE(0, 0);

  #pragma unroll
  for (int ks = 0; ks < 8; ++ks) {
    const int cur = ks & 1;
    __builtin_amdgcn_s_barrier();          // all waves done reading buf cur^1
    if (ks < 7) {
      STAGE(ks + 1, cur ^ 1);              // prefetch next step into the freed buffer
      asm volatile("s_waitcnt vmcnt(4)" ::: "memory");  // wait only for stage(ks)
    } else {
      asm volatile("s_waitcnt vmcnt(0)" ::: "memory");
    }
    __builtin_amdgcn_sched_barrier(0);

    bf16x8 a[4], b[4];
    #pragma unroll
    for (int mi = 0; mi < 4; ++mi) {
      int R = wm * 64 + mi * 16 + l15;
      a[mi] = *reinterpret_cast<const bf16x8*>(Ah[cur] + R * 32 + ((lhi ^ ((R >> 1) & 3)) * 8));
    }
    #pragma unroll
    for (int ni = 0; ni < 4; ++ni) {
      int R = wn * 64 + ni * 16 + l15;
      b[ni] = *reinterpret_cast<const bf16x8*>(Bh[cur] + R * 32 + ((lhi ^ ((R >> 1) & 3)) * 8));
    }
    #pragma unroll
    for (int mi = 0; mi < 4; ++mi)
      #pragma unroll
      for (int ni = 0; ni < 4; ++ni)
        acc[mi][ni] = __builtin_amdgcn_mfma_f32_16x16x32_bf16(a[mi], b[ni], acc[mi][ni], 0, 0, 0);
  }
#undef STAGE

  // ---- epilogue: scalesq (off the startup critical path) ----
  const float scalesq = block_scalesq(bbp, bbn, red, tid);
  const float thrP = 30.0f * scalesq * 0.2f + 2.5f * scalesq + 0.5f;

  float bbc[4];
  #pragma unroll
  for (int ni = 0; ni < 4; ++ni) bbc[ni] = bbv[cf + wn * 64 + ni * 16 + l15];

  #pragma unroll
  for (int mi = 0; mi < 4; ++mi)
    #pragma unroll
    for (int r = 0; r < 4; ++r) {
      float uv[4];
      float mx = -3.0e38f;
      #pragma unroll
      for (int ni = 0; ni < 4; ++ni) {
        uv[ni] = 2.0f * acc[mi][ni][r] - bbc[ni];
        mx = fmaxf(mx, uv[ni]);
      }
      #pragma unroll
      for (int off = 1; off < 16; off <<= 1) mx = fmaxf(mx, __shfl_xor(mx, off));
      const float cut = mx - thrP;

      u64 bal[4];
      #pragma unroll
      for (int ni = 0; ni < 4; ++ni) bal[ni] = __ballot(uv[ni] > cut);

      u64 mask = 0;
      #pragma unroll
      for (int ni = 0; ni < 4; ++ni)
        mask |= ((bal[ni] >> (lhi * 16)) & 0xFFFFull) << (ni * 16);

      const int rowG = rf + wm * 64 + mi * 16 + lhi * 4 + r;
      if (l15 == 0) {
        // transposed layout [side][row][til]: row_kernel lane t reads tile t coalesced
        Kmask[((size_t)side * NPTS + rowG) * TIL + til] = mask;
        M[((size_t)side * NPTS + rowG) * TIL + til] = mx;
      }
    }
}

// ---------- K3: wave-per-row; PARALLEL mask harvest (lane t owns tile t) ----------
__global__ __launch_bounds__(256) void row_kernel(
    const float* __restrict__ M, const u64* __restrict__ Kmask,
    const float* __restrict__ bbp, const float* __restrict__ bbn,
    const float* __restrict__ x,
    const float* __restrict__ ypos, const float* __restrict__ yneg,
    float* __restrict__ parts, float* __restrict__ Vout)
{
  __shared__ unsigned cl[4][2][WCAND];
  __shared__ float red[4];

  const int tid  = threadIdx.x;
  const int lane = tid & 63;
  const int w    = tid >> 6;
  const int row  = blockIdx.x * 4 + w;

  // issue all harvest loads up front (coalesced, both sides in flight)
  float Mv[2]; u64 km[2];
  #pragma unroll
  for (int side = 0; side < 2; ++side) {
    Mv[side] = M[((size_t)side * NPTS + row) * TIL + lane];
    km[side] = Kmask[((size_t)side * NPTS + row) * TIL + lane];
  }
  const f32x4 xv = *reinterpret_cast<const f32x4*>(x + (size_t)row * DIM + lane * 4);

  const float scalesq = block_scalesq(bbp, bbn, red, tid);  // overlaps the loads above
  const float L2E = 1.4426950408889634f;
  const float c0 = L2E / (scalesq * 0.02f);
  const float c1 = L2E / (scalesq * 0.05f);
  const float c2 = L2E / (scalesq * 0.2f);
  const float thrP = 30.0f * scalesq * 0.2f + 2.5f * scalesq + 0.5f;

  // parallel harvest: lane t owns tile t; prefix-sum compaction
  int ncs[2];
  #pragma unroll
  for (int side = 0; side < 2; ++side) {
    float g = Mv[side];
    #pragma unroll
    for (int off = 32; off; off >>= 1) g = fmaxf(g, __shfl_xor(g, off));
    u64 mk = (Mv[side] > g - thrP) ? km[side] : 0ull;
    int mycnt = __popcll(mk);
    int pfx = mycnt;
    #pragma unroll
    for (int off = 1; off < 64; off <<= 1) {
      int t = __shfl_up(pfx, off);
      if (lane >= off) pfx += t;
    }
    int base = pfx - mycnt;
    int nc = __shfl(pfx, 63);
    u64 b = mk;
    int s = base;
    while (b) {
      int bit = __ffsll((long long)b) - 1;
      b &= b - 1;
      if (s < WCAND) cl[w][side][s] = lane * 64 + bit;
      ++s;
    }
    ncs[side] = nc < WCAND ? nc : WCAND;
  }
  // same-wave LDS write->read; DS pipe in-order per wave

  f32x4 V0 = {0,0,0,0}, V1 = {0,0,0,0}, V2 = {0,0,0,0};

  for (int side = 0; side < 2; ++side) {
    const float* bb = side ? bbn : bbp;
    const float* y  = side ? yneg : ypos;
    const float sgn = side ? -1.f : 1.f;
    const int nc = ncs[side];

    // chunks of 8 candidates, y rows register-resident, online-rescaled softmax
    float me = -3.0e38f, p0 = 0.f, p1 = 0.f, p2 = 0.f;
    f32x4 A0 = {0,0,0,0}, A1 = {0,0,0,0}, A2 = {0,0,0,0};
    for (int bs = 0; bs < nc; bs += 8) {
      const int rem = nc - bs;
      int jq[8];
      f32x4 yv[8];
      float dq[8], uq[8];
      #pragma unroll
      for (int q = 0; q < 8; ++q) {
        int idx = (q < rem) ? bs + q : bs;
        jq[q] = (int)cl[w][side][idx];
        yv[q] = *reinterpret_cast<const f32x4*>(y + (size_t)jq[q] * DIM + lane * 4);
      }
      #pragma unroll
      for (int q = 0; q < 8; ++q)
        dq[q] = xv[0]*yv[q][0] + xv[1]*yv[q][1] + xv[2]*yv[q][2] + xv[3]*yv[q][3];
      #pragma unroll
      for (int off = 32; off; off >>= 1)
        #pragma unroll
        for (int q = 0; q < 8; ++q) dq[q] += __shfl_xor(dq[q], off);
      #pragma unroll
      for (int q = 0; q < 8; ++q)
        uq[q] = (q < rem) ? 2.0f * dq[q] - bb[jq[q]] : -3.0e38f;

      float cm = uq[0];
      #pragma unroll
      for (int q = 1; q < 8; ++q) cm = fmaxf(cm, uq[q]);
      float nm = fmaxf(me, cm);
      float s0 = exp2fast((me - nm) * c0);
      float s1 = exp2fast((me - nm) * c1);
      float s2 = exp2fast((me - nm) * c2);
      p0 *= s0; p1 *= s1; p2 *= s2;
      A0 *= s0; A1 *= s1; A2 *= s2;
      #pragma unroll
      for (int q = 0; q < 8; ++q) {
        float du = uq[q] - nm;
        float e0 = exp2fast(du * c0);
        float e1 = exp2fast(du * c1);
        float e2 = exp2fast(du * c2);
        p0 += e0; p1 += e1; p2 += e2;
        A0 += e0 * yv[q]; A1 += e1 * yv[q]; A2 += e2 * yv[q];
      }
      me = nm;
    }
    V0 += (sgn / p0) * A0;
    V1 += (sgn / p1) * A1;
    V2 += (sgn / p2) * A2;
  }

  f32x4 vr = (V0 + V1 + V2) * (1.0f / 3.0f);
  *reinterpret_cast<f32x4*>(Vout + (size_t)row * DIM + lane * 4) = vr;

  float s0 = V0[0]*V0[0] + V0[1]*V0[1] + V0[2]*V0[2] + V0[3]*V0[3];
  float s1 = V1[0]*V1[0] + V1[1]*V1[1] + V1[2]*V1[2] + V1[3]*V1[3];
  float s2 = V2[0]*V2[0] + V2[1]*V2[1] + V2[2]*V2[2] + V2[3]*V2[3];
  float sr = vr[0]*vr[0] + vr[1]*vr[1] + vr[2]*vr[2] + vr[3]*vr[3];
  #pragma unroll
  for (int off = 32; off; off >>= 1) {
    s0 += __shfl_xor(s0, off);
    s1 += __shfl_xor(s1, off);
    s2 += __shfl_xor(s2, off);
    sr += __shfl_xor(sr, off);
  }
  if (lane == 0) {
    parts[row]            = sr;
    parts[NPTS + row]     = s0;
    parts[2 * NPTS + row] = s1;
    parts[3 * NPTS + row] = s2;
  }
}

// ---------- K4: fused reduce + finalize + V scale ----------
__global__ __launch_bounds__(256) void final_kernel(
    const float* __restrict__ parts, float* __restrict__ out)
{
  __shared__ float red[4];
  const int tid = threadIdx.x;

  float s = 0.f;
  for (int k = tid; k < NPTS; k += 256) s += parts[k];
  float raw = blk_sum4(s, red) * (1.0f / NPTS);
  float lam2 = raw * (1.0f / DIM) + 1e-8f;
  float lam  = sqrtf(lam2);
  float inv  = 1.0f / lam;

  int idx = blockIdx.x * 256 + tid;
  out[7 + idx] *= inv;

  if (blockIdx.x == 0) {
    #pragma unroll
    for (int a = 1; a <= 3; ++a) {
      float t = 0.f;
      for (int k = tid; k < NPTS; k += 256) t += parts[a * NPTS + k];
      t = blk_sum4(t, red);
      if (tid == 0) out[3 + a] = t * (1.0f / NPTS);
    }
    if (tid == 0) {
      float drift = raw / lam2;
      out[0] = drift * (1.0f / DIM);
      out[1] = drift;
      out[2] = raw;
      out[3] = lam;
    }
  }
}

extern "C" void kernel_launch(void* const* d_in, const int* in_sizes, int n_in,
                              void* d_out, int out_size, void* d_ws, size_t ws_size,
                              hipStream_t stream)
{
  (void)in_sizes; (void)n_in; (void)out_size; (void)ws_size;
  const float* x    = (const float*)d_in[0];
  const float* ypos = (const float*)d_in[1];
  const float* yneg = (const float*)d_in[2];
  float* out = (float*)d_out;
  char* ws = (char*)d_ws;

  // ws layout (M/Kmask fully rewritten each launch; no zeroing needed):
  // bbp 16K | bbn 16K | parts 64K | M 2M | Kmask 4M | xb/ypb/ynb 6M
  float* bbp   = (float*)ws;
  float* bbn   = (float*)(ws + 16384);
  float* parts = (float*)(ws + 32768);
  float* M     = (float*)(ws + 98304);
  u64*   Kmask = (u64*)(ws + 98304 + 2097152);
  u16* xb  = (u16*)(ws + 98304 + 2097152 + 4194304);
  u16* ypb = xb + (size_t)NPTS * DIM;
  u16* ynb = xb + 2 * (size_t)NPTS * DIM;

  split3_kernel<<<dim3(NPTS / 4, 3), 256, 0, stream>>>(x, ypos, yneg, xb, ypb, ynb, bbp, bbn);
  gemm_kernel<<<dim3(32, 32, 2), 256, 0, stream>>>(xb, ypb, ynb, bbp, bbn, M, Kmask);
  row_kernel<<<NPTS / 4, 256, 0, stream>>>(M, Kmask, bbp, bbn, x, ypos, yneg,
                                           parts, out + 7);
  final_kernel<<<NPTS, 256, 0, stream>>>(parts, out);
}